// Round 4
// baseline (1153.566 us; speedup 1.0000x reference)
//
#include <hip/hip_runtime.h>
#include <hip/hip_bf16.h>

typedef __attribute__((ext_vector_type(8))) short bf16x8;
typedef __attribute__((ext_vector_type(4))) float f32x4;

#define NW_   3072
#define WACT_ 1536
#define NTOK_ 98304
#define NBLK_ 9830
#define DIM_  384
#define QKVD_ 1152
#define MLPD_ 1536
#define TM_   4

__device__ __forceinline__ float bf2f(short s) {
  union { unsigned u; float f; } c;
  c.u = ((unsigned)(unsigned short)s) << 16;
  return c.f;
}
__device__ __forceinline__ short f2bf(float f) {
  union { float f; unsigned u; } c; c.f = f;
  unsigned lsb = (c.u >> 16) & 1u;
  c.u += 0x7fffu + lsb;
  return (short)(c.u >> 16);
}

__device__ __forceinline__ f32x4 mfma16(bf16x8 a, bf16x8 b, f32x4 c) {
  return __builtin_amdgcn_mfma_f32_16x16x32_bf16(a, b, c, 0, 0, 0);
}

__device__ __forceinline__ void gload16(const void* g, void* l) {
  __builtin_amdgcn_global_load_lds(
      (const __attribute__((address_space(1))) unsigned*)g,
      (__attribute__((address_space(3))) unsigned*)l, 16, 0, 0);
}

// ---------------- map kernels ----------------
__global__ __launch_bounds__(256) void mapA_k(int* win_rank, unsigned* bitmap) {
  int t = blockIdx.x * 256 + threadIdx.x;
  if (t < NW_) { win_rank[t] = -1; bitmap[t] = 0u; }
}

__global__ __launch_bounds__(256) void mapB_k(const int* __restrict__ iw,
                                              const int* __restrict__ blk,
                                              int* win_rank, unsigned* bitmap) {
  int t = blockIdx.x * 256 + threadIdx.x;
  if (t < WACT_) win_rank[iw[t]] = t;
  if (t < NBLK_) { int j = blk[t]; atomicOr(&bitmap[j >> 5], 1u << (j & 31)); }
}

__global__ __launch_bounds__(256) void mapC_k(const int* __restrict__ ip,
                                              const int* __restrict__ iw,
                                              const unsigned* __restrict__ bitmap,
                                              int* inv_ip, int* rowmap) {
  int i = blockIdx.x * 256 + threadIdx.x;
  if (i < NTOK_) {
    int j = ip[i];
    inv_ip[j] = i;
    int blocked = (bitmap[j >> 5] >> (j & 31)) & 1;
    rowmap[i] = blocked ? -1 : (iw[j >> 6] * 64 + (j & 63));
  }
}

// ---------------- weight conversion ----------------
__global__ __launch_bounds__(256) void wconv_k(const float* __restrict__ qkvw,
                                               const float* __restrict__ projw,
                                               const float* __restrict__ fc1w,
                                               const float* __restrict__ fc2w,
                                               short* __restrict__ dst) {
  int i = blockIdx.x * 256 + threadIdx.x;  // total 1,769,472
  float v;
  if (i < 442368) v = qkvw[i];
  else if (i < 589824) v = projw[i - 442368];
  else if (i < 1179648) v = fc1w[i - 589824];
  else v = fc2w[i - 1179648];
  dst[i] = f2bf(v);
}

// ---------------- LN1 + gather/permute ----------------
__global__ __launch_bounds__(256) void ln1_k(const float* __restrict__ x,
                                             const float* __restrict__ w,
                                             const float* __restrict__ b,
                                             const int* __restrict__ win_rank,
                                             const int* __restrict__ inv_ip,
                                             const unsigned* __restrict__ bitmap,
                                             float* __restrict__ out,
                                             short* __restrict__ xp) {
  int lane = threadIdx.x & 63;
  int tok = (blockIdx.x << 2) + (threadIdx.x >> 6);
  const float* xr = x + (size_t)tok * DIM_;
  float v[6]; float s = 0.f;
#pragma unroll
  for (int j = 0; j < 6; ++j) { v[j] = xr[lane + 64 * j]; s += v[j]; }
#pragma unroll
  for (int m = 1; m < 64; m <<= 1) s += __shfl_xor(s, m, 64);
  float mu = s * (1.0f / DIM_);
  float q = 0.f;
#pragma unroll
  for (int j = 0; j < 6; ++j) { float d = v[j] - mu; q += d * d; }
#pragma unroll
  for (int m = 1; m < 64; m <<= 1) q += __shfl_xor(q, m, 64);
  float rs = rsqrtf(q * (1.0f / DIM_) + 1e-5f);
  float y[6];
#pragma unroll
  for (int j = 0; j < 6; ++j)
    y[j] = (v[j] - mu) * rs * w[lane + 64 * j] + b[lane + 64 * j];
  int wdw = tok >> 6, t = tok & 63;
  int rank = win_rank[wdw];
  if (rank < 0) {
#pragma unroll
    for (int j = 0; j < 6; ++j) out[(size_t)tok * DIM_ + lane + 64 * j] = y[j];
  } else {
    int jdx = (rank << 6) + t;
    int i = inv_ip[jdx];
#pragma unroll
    for (int j = 0; j < 6; ++j) xp[(size_t)i * DIM_ + lane + 64 * j] = f2bf(y[j]);
    if ((bitmap[jdx >> 5] >> (jdx & 31)) & 1) {
#pragma unroll
      for (int j = 0; j < 6; ++j) out[(size_t)tok * DIM_ + lane + 64 * j] = y[j];
    }
  }
}

// ---------------- LN2 ----------------
__global__ __launch_bounds__(256) void ln2_k(const short* __restrict__ h,
                                             const float* __restrict__ w,
                                             const float* __restrict__ b,
                                             short* __restrict__ outln) {
  int lane = threadIdx.x & 63;
  int tok = (blockIdx.x << 2) + (threadIdx.x >> 6);
  const short* xr = h + (size_t)tok * DIM_;
  float v[6]; float s = 0.f;
#pragma unroll
  for (int j = 0; j < 6; ++j) { v[j] = bf2f(xr[lane + 64 * j]); s += v[j]; }
#pragma unroll
  for (int m = 1; m < 64; m <<= 1) s += __shfl_xor(s, m, 64);
  float mu = s * (1.0f / DIM_);
  float q = 0.f;
#pragma unroll
  for (int j = 0; j < 6; ++j) { float d = v[j] - mu; q += d * d; }
#pragma unroll
  for (int m = 1; m < 64; m <<= 1) q += __shfl_xor(q, m, 64);
  float rs = rsqrtf(q * (1.0f / DIM_) + 1e-5f);
#pragma unroll
  for (int j = 0; j < 6; ++j) {
    float y = (v[j] - mu) * rs * w[lane + 64 * j] + b[lane + 64 * j];
    outln[(size_t)tok * DIM_ + lane + 64 * j] = f2bf(y);
  }
}

// ---------------- GEMM: C = A[98304,K] * B[N,K]^T ----------------
// 128x128 tile (m97 structure), TM_=4 mtiles per block (persistent pipeline:
// prologue/epilogue amortized over TM_*nkt tiles), double-buffered LDS,
// counted s_waitcnt vmcnt(8) (never 0 in main loop), raw s_barrier,
// XCD-chunk swizzle (A-panel shared within an XCD's contiguous wg range).
// EPI 0: +bias -> bf16 (ld N)        (QKV)
// EPI 1: +bias +add_bf -> bf16       (proj + residual -> h)
// EPI 2: +bias, gelu -> bf16         (fc1)
// EPI 3: +bias +add_bf, scatter fp32 (fc2 + residual -> out)
template <int EPI>
__global__ __launch_bounds__(256) void gemm_k(const short* __restrict__ A,
                                              const short* __restrict__ B,
                                              const float* __restrict__ bias,
                                              int K, int N, int nx,
                                              short* __restrict__ Cb,
                                              const short* __restrict__ add_bf,
                                              const int* __restrict__ rowmap,
                                              float* __restrict__ outf) {
  const int nwg = gridDim.x;
  const int q8 = nwg >> 3;
  const int wg = (blockIdx.x & 7) * q8 + (blockIdx.x >> 3);
  const int ntile = wg % nx, mg = wg / nx;
  const int tid = threadIdx.x, wid = tid >> 6, lane = tid & 63;
  const int fq = lane >> 4, fr = lane & 15;
  const int wr = wid >> 1, wc = wid & 1;
  __shared__ __align__(16) short lA[2][128 * 64];
  __shared__ __align__(16) short lB[2][128 * 64];
  const int col0 = ntile * 128;
  float bs[4];
#pragma unroll
  for (int nt = 0; nt < 4; ++nt) bs[nt] = bias[col0 + wc * 64 + nt * 16 + fr];
  f32x4 acc[4][4];
#pragma unroll
  for (int a = 0; a < 4; ++a)
#pragma unroll
    for (int c = 0; c < 4; ++c) acc[a][c] = (f32x4){0.f, 0.f, 0.f, 0.f};

  // 8 gload16 per thread per K-tile (A:4, B:4)
  auto stage = [&](int buf, int mtile, int kt) {
    const int k0 = kt << 6;
    const int row0 = mtile * 128;
#pragma unroll
    for (int i = 0; i < 4; ++i) {
      int cb = ((i * 4 + wid) << 6) + lane;
      int r = cb >> 3, c8 = cb & 7;
      int s8 = c8 ^ (r & 7);
      gload16(A + (size_t)(row0 + r) * K + k0 + s8 * 8,
              (char*)lA[buf] + (size_t)(i * 4 + wid) * 1024);
      gload16(B + (size_t)(col0 + r) * K + k0 + s8 * 8,
              (char*)lB[buf] + (size_t)(i * 4 + wid) * 1024);
    }
  };
  auto compute = [&](int buf) {
#pragma unroll
    for (int ks = 0; ks < 2; ++ks) {
      bf16x8 af[4], bfr[4];
      int swz = fr & 7;
#pragma unroll
      for (int mt = 0; mt < 4; ++mt)
        af[mt] = *(const bf16x8*)&lA[buf][(wr * 64 + mt * 16 + fr) * 64 +
                                          ((ks * 4 + fq) ^ swz) * 8];
#pragma unroll
      for (int nt = 0; nt < 4; ++nt)
        bfr[nt] = *(const bf16x8*)&lB[buf][(wc * 64 + nt * 16 + fr) * 64 +
                                           ((ks * 4 + fq) ^ swz) * 8];
#pragma unroll
      for (int mt = 0; mt < 4; ++mt)
#pragma unroll
        for (int nt = 0; nt < 4; ++nt)
          acc[mt][nt] = mfma16(af[mt], bfr[nt], acc[mt][nt]);
    }
  };

  const int nkt = K >> 6;
  const int total = TM_ * nkt;
  stage(0, mg * TM_, 0);
  int t = 0;
  for (int mi = 0; mi < TM_; ++mi) {
    const int mtile = mg * TM_ + mi;
    for (int kt = 0; kt < nkt; ++kt, ++t) {
      const int cur = t & 1;
      if (t + 1 < total) {
        const int last = (kt == nkt - 1);
        stage(cur ^ 1, mtile + last, last ? 0 : kt + 1);
        asm volatile("s_waitcnt vmcnt(8)" ::: "memory");
      } else {
        asm volatile("s_waitcnt vmcnt(0)" ::: "memory");
      }
      asm volatile("s_barrier" ::: "memory");
      compute(cur);
      if (kt == nkt - 1) {
        // epilogue for this mtile, then reset acc
        const int row0 = mtile * 128;
#pragma unroll
        for (int mt = 0; mt < 4; ++mt) {
#pragma unroll
          for (int jj = 0; jj < 4; ++jj) {
            int r = row0 + wr * 64 + mt * 16 + fq * 4 + jj;
            int dmap = 0;
            if (EPI == 3) dmap = rowmap[r];
#pragma unroll
            for (int nt = 0; nt < 4; ++nt) {
              int gcol = col0 + wc * 64 + nt * 16 + fr;
              float v = acc[mt][nt][jj] + bs[nt];
              if (EPI == 0) {
                Cb[(size_t)r * N + gcol] = f2bf(v);
              } else if (EPI == 1) {
                v += bf2f(add_bf[(size_t)r * DIM_ + gcol]);
                Cb[(size_t)r * DIM_ + gcol] = f2bf(v);
              } else if (EPI == 2) {
                float u = v * (0.79788456f + 0.03567741f * v * v);
                float g = v * __builtin_amdgcn_rcpf(1.0f + __expf(-2.0f * u));
                Cb[(size_t)r * MLPD_ + gcol] = f2bf(g);
              } else {
                v += bf2f(add_bf[(size_t)r * DIM_ + gcol]);
                if (dmap >= 0) outf[(size_t)dmap * DIM_ + gcol] = v;
              }
            }
          }
        }
#pragma unroll
        for (int a = 0; a < 4; ++a)
#pragma unroll
          for (int c = 0; c < 4; ++c) acc[a][c] = (f32x4){0.f, 0.f, 0.f, 0.f};
      }
      asm volatile("s_barrier" ::: "memory");
    }
  }
}

// ---------------- attention ----------------
__global__ __launch_bounds__(256) void attn_k(const short* __restrict__ qkv,
                                              const unsigned* __restrict__ bitmap,
                                              const int* __restrict__ ip,
                                              short* __restrict__ o) {
  const int m = blockIdx.x;
  const int wid = threadIdx.x >> 6, lane = threadIdx.x & 63;
  const int fq = lane >> 4, fr = lane & 15;
  __shared__ __align__(16) short P[4][64 * 72];
  __shared__ __align__(16) short Vt[4][32 * 72];
  __shared__ unsigned char flags[64];
  if (threadIdx.x < 64) {
    int j = ip[m * 64 + threadIdx.x];
    flags[threadIdx.x] = (unsigned char)((bitmap[j >> 5] >> (j & 31)) & 1);
  }
  __syncthreads();
  const float scale = 0.17677669529663687f;
  int msk[4];
#pragma unroll
  for (int nt = 0; nt < 4; ++nt) msk[nt] = flags[nt * 16 + fr];

  for (int hh = 0; hh < 3; ++hh) {
    int h = wid * 3 + hh;
    const short* base = qkv + (size_t)m * 64 * QKVD_ + h * 96;
    // ---- S = Q K^T ----
    f32x4 sacc[4][4];
#pragma unroll
    for (int a = 0; a < 4; ++a)
#pragma unroll
      for (int c = 0; c < 4; ++c) sacc[a][c] = (f32x4){0.f, 0.f, 0.f, 0.f};
    bf16x8 qa[4], kb[4];
#pragma unroll
    for (int mt = 0; mt < 4; ++mt)
      qa[mt] = *(const bf16x8*)(base + (size_t)(mt * 16 + fr) * QKVD_ + fq * 8);
#pragma unroll
    for (int nt = 0; nt < 4; ++nt)
      kb[nt] = *(const bf16x8*)(base + (size_t)(nt * 16 + fr) * QKVD_ + 32 + fq * 8);
#pragma unroll
    for (int mt = 0; mt < 4; ++mt)
#pragma unroll
      for (int nt = 0; nt < 4; ++nt)
        sacc[mt][nt] = mfma16(qa[mt], kb[nt], sacc[mt][nt]);
    // ---- stage V transposed ----
#pragma unroll
    for (int c = 0; c < 4; ++c) {
      bf16x8 vv = *(const bf16x8*)(base + (size_t)lane * QKVD_ + 64 + c * 8);
#pragma unroll
      for (int e = 0; e < 8; ++e) Vt[wid][(c * 8 + e) * 72 + lane] = vv[e];
    }
    // ---- scale + mask (in place) ----
#pragma unroll
    for (int mt = 0; mt < 4; ++mt)
#pragma unroll
      for (int nt = 0; nt < 4; ++nt) {
        f32x4 sv = sacc[mt][nt];
#pragma unroll
        for (int jj = 0; jj < 4; ++jj)
          sv[jj] = msk[nt] ? -10000.0f : sv[jj] * scale;
        sacc[mt][nt] = sv;
      }
    // ---- softmax rows + write P ----
#pragma unroll
    for (int mt = 0; mt < 4; ++mt) {
#pragma unroll
      for (int jj = 0; jj < 4; ++jj) {
        float mx = sacc[mt][0][jj];
#pragma unroll
        for (int nt = 1; nt < 4; ++nt) mx = fmaxf(mx, sacc[mt][nt][jj]);
#pragma unroll
        for (int mm = 1; mm < 16; mm <<= 1) mx = fmaxf(mx, __shfl_xor(mx, mm, 64));
        float sm = 0.f;
        float p[4];
#pragma unroll
        for (int nt = 0; nt < 4; ++nt) {
          p[nt] = __expf(sacc[mt][nt][jj] - mx);
          sm += p[nt];
        }
#pragma unroll
        for (int mm = 1; mm < 16; mm <<= 1) sm += __shfl_xor(sm, mm, 64);
        float inv = 1.0f / sm;
        int rowb = (mt * 16 + fq * 4 + jj) * 72;
#pragma unroll
        for (int nt = 0; nt < 4; ++nt)
          P[wid][rowb + nt * 16 + fr] = f2bf(p[nt] * inv);
      }
    }
    // ---- O = P V ----
    f32x4 oacc[4][2];
#pragma unroll
    for (int a = 0; a < 4; ++a)
#pragma unroll
      for (int c = 0; c < 2; ++c) oacc[a][c] = (f32x4){0.f, 0.f, 0.f, 0.f};
#pragma unroll
    for (int ks = 0; ks < 2; ++ks) {
      bf16x8 pa[4], vb[2];
#pragma unroll
      for (int mt = 0; mt < 4; ++mt)
        pa[mt] = *(const bf16x8*)&P[wid][(mt * 16 + fr) * 72 + ks * 32 + fq * 8];
#pragma unroll
      for (int nd = 0; nd < 2; ++nd)
        vb[nd] = *(const bf16x8*)&Vt[wid][(nd * 16 + fr) * 72 + ks * 32 + fq * 8];
#pragma unroll
      for (int mt = 0; mt < 4; ++mt)
#pragma unroll
        for (int nd = 0; nd < 2; ++nd)
          oacc[mt][nd] = mfma16(pa[mt], vb[nd], oacc[mt][nd]);
    }
    // ---- store O ----
#pragma unroll
    for (int mt = 0; mt < 4; ++mt)
#pragma unroll
      for (int nd = 0; nd < 2; ++nd)
#pragma unroll
        for (int jj = 0; jj < 4; ++jj)
          o[(size_t)(m * 64 + mt * 16 + fq * 4 + jj) * DIM_ + h * 32 + nd * 16 + fr] =
              f2bf(oacc[mt][nd][jj]);
  }
}

// ---------------- launch ----------------
extern "C" void kernel_launch(void* const* d_in, const int* in_sizes, int n_in,
                              void* d_out, int out_size, void* d_ws, size_t ws_size,
                              hipStream_t stream) {
  const float* x = (const float*)d_in[0];
  const int* iw = (const int*)d_in[1];
  const int* ip = (const int*)d_in[2];
  const int* blk = (const int*)d_in[3];
  const float* ln1w = (const float*)d_in[6];
  const float* ln1b = (const float*)d_in[7];
  const float* qkvw = (const float*)d_in[8];
  const float* qkvb = (const float*)d_in[9];
  const float* projw = (const float*)d_in[10];
  const float* projb = (const float*)d_in[11];
  const float* ln2w = (const float*)d_in[12];
  const float* ln2b = (const float*)d_in[13];
  const float* fc1w = (const float*)d_in[14];
  const float* fc1b = (const float*)d_in[15];
  const float* fc2w = (const float*)d_in[16];
  const float* fc2b = (const float*)d_in[17];
  float* out = (float*)d_out;

  char* ws = (char*)d_ws;
  short* w_all = (short*)ws;                 // 1,769,472 bf16
  short* w_qkv = w_all;
  short* w_proj = w_all + 442368;
  short* w_fc1 = w_all + 589824;
  short* w_fc2 = w_all + 1179648;
  int* inv_ip = (int*)(ws + 3538944);
  int* rowmap = inv_ip + NTOK_;
  int* win_rank = rowmap + NTOK_;
  unsigned* bitmap = (unsigned*)(win_rank + NW_);
  short* xp = (short*)(ws + 4349952);                        // 75.5 MB (also ln2 out later)
  short* qkv_g = (short*)(ws + 4349952 + 75497472);          // 302 MB region (qkv, then gelu)
  short* obuf = (short*)(ws + 381837312);                    // 75.5 MB
  short* hbuf = (short*)(ws + 457334784);                    // 75.5 MB
  short* ln2buf = xp;
  (void)in_sizes; (void)n_in; (void)out_size; (void)ws_size;

  mapA_k<<<12, 256, 0, stream>>>(win_rank, bitmap);
  mapB_k<<<39, 256, 0, stream>>>(iw, blk, win_rank, bitmap);
  mapC_k<<<NTOK_ / 256, 256, 0, stream>>>(ip, iw, bitmap, inv_ip, rowmap);
  wconv_k<<<6912, 256, 0, stream>>>(qkvw, projw, fc1w, fc2w, w_all);
  ln1_k<<<(NW_ * 64) / 4, 256, 0, stream>>>(x, ln1w, ln1b, win_rank, inv_ip, bitmap,
                                            out, xp);
  // mgroups = 98304 / (128*TM_) = 192; grid = mgroups * nx (all % 8 == 0)
  gemm_k<0><<<192 * 9, 256, 0, stream>>>(xp, w_qkv, qkvb, 384, QKVD_, 9, qkv_g,
                                         nullptr, nullptr, nullptr);
  attn_k<<<WACT_, 256, 0, stream>>>(qkv_g, bitmap, ip, obuf);
  gemm_k<1><<<192 * 3, 256, 0, stream>>>(obuf, w_proj, projb, 384, DIM_, 3, hbuf,
                                         xp, nullptr, nullptr);
  ln2_k<<<NTOK_ / 4, 256, 0, stream>>>(hbuf, ln2w, ln2b, ln2buf);
  gemm_k<2><<<192 * 12, 256, 0, stream>>>(ln2buf, w_fc1, fc1b, 384, MLPD_, 12, qkv_g,
                                          nullptr, nullptr, nullptr);
  gemm_k<3><<<192 * 3, 256, 0, stream>>>(qkv_g, w_fc2, fc2b, 1536, DIM_, 3, nullptr,
                                         hbuf, rowmap, out);
}

// Round 6
// 1080.628 us; speedup vs baseline: 1.0675x; 1.0675x over previous
//
#include <hip/hip_runtime.h>
#include <hip/hip_bf16.h>

typedef __attribute__((ext_vector_type(8))) short bf16x8;
typedef __attribute__((ext_vector_type(4))) float f32x4;

#define NW_   3072
#define WACT_ 1536
#define NTOK_ 98304
#define NBLK_ 9830
#define DIM_  384
#define QKVD_ 1152
#define MLPD_ 1536

#define WAITSYNC() do { asm volatile("s_waitcnt vmcnt(0) lgkmcnt(0)" ::: "memory"); __syncthreads(); } while (0)

__device__ __forceinline__ float bf2f(short s) {
  union { unsigned u; float f; } c;
  c.u = ((unsigned)(unsigned short)s) << 16;
  return c.f;
}
__device__ __forceinline__ short f2bf(float f) {
  union { float f; unsigned u; } c; c.f = f;
  unsigned lsb = (c.u >> 16) & 1u;
  c.u += 0x7fffu + lsb;
  return (short)(c.u >> 16);
}

__device__ __forceinline__ f32x4 mfma16(bf16x8 a, bf16x8 b, f32x4 c) {
  return __builtin_amdgcn_mfma_f32_16x16x32_bf16(a, b, c, 0, 0, 0);
}

__device__ __forceinline__ void gload16(const void* g, void* l) {
  __builtin_amdgcn_global_load_lds(
      (const __attribute__((address_space(1))) unsigned*)g,
      (__attribute__((address_space(3))) unsigned*)l, 16, 0, 0);
}

// ---------------- map kernels ----------------
__global__ __launch_bounds__(256) void mapA_k(int* win_rank, unsigned* bitmap) {
  int t = blockIdx.x * 256 + threadIdx.x;
  if (t < NW_) { win_rank[t] = -1; bitmap[t] = 0u; }
}

__global__ __launch_bounds__(256) void mapB_k(const int* __restrict__ iw,
                                              const int* __restrict__ blk,
                                              int* win_rank, unsigned* bitmap) {
  int t = blockIdx.x * 256 + threadIdx.x;
  if (t < WACT_) win_rank[iw[t]] = t;
  if (t < NBLK_) { int j = blk[t]; atomicOr(&bitmap[j >> 5], 1u << (j & 31)); }
}

__global__ __launch_bounds__(256) void mapC_k(const int* __restrict__ ip,
                                              const int* __restrict__ iw,
                                              const unsigned* __restrict__ bitmap,
                                              int* inv_ip, int* rowmap) {
  int i = blockIdx.x * 256 + threadIdx.x;
  if (i < NTOK_) {
    int j = ip[i];
    inv_ip[j] = i;
    int blocked = (bitmap[j >> 5] >> (j & 31)) & 1;
    rowmap[i] = blocked ? -1 : (iw[j >> 6] * 64 + (j & 63));
  }
}

// ---------------- weight conversion ----------------
__global__ __launch_bounds__(256) void wconv_k(const float* __restrict__ qkvw,
                                               const float* __restrict__ projw,
                                               const float* __restrict__ fc1w,
                                               const float* __restrict__ fc2w,
                                               short* __restrict__ dst) {
  int i = blockIdx.x * 256 + threadIdx.x;  // total 1,769,472
  float v;
  if (i < 442368) v = qkvw[i];
  else if (i < 589824) v = projw[i - 442368];
  else if (i < 1179648) v = fc1w[i - 589824];
  else v = fc2w[i - 1179648];
  dst[i] = f2bf(v);
}

// ---------------- LN1 + gather/permute ----------------
__global__ __launch_bounds__(256) void ln1_k(const float* __restrict__ x,
                                             const float* __restrict__ w,
                                             const float* __restrict__ b,
                                             const int* __restrict__ win_rank,
                                             const int* __restrict__ inv_ip,
                                             const unsigned* __restrict__ bitmap,
                                             float* __restrict__ out,
                                             short* __restrict__ xp) {
  int lane = threadIdx.x & 63;
  int tok = (blockIdx.x << 2) + (threadIdx.x >> 6);
  const float* xr = x + (size_t)tok * DIM_;
  float v[6]; float s = 0.f;
#pragma unroll
  for (int j = 0; j < 6; ++j) { v[j] = xr[lane + 64 * j]; s += v[j]; }
#pragma unroll
  for (int m = 1; m < 64; m <<= 1) s += __shfl_xor(s, m, 64);
  float mu = s * (1.0f / DIM_);
  float q = 0.f;
#pragma unroll
  for (int j = 0; j < 6; ++j) { float d = v[j] - mu; q += d * d; }
#pragma unroll
  for (int m = 1; m < 64; m <<= 1) q += __shfl_xor(q, m, 64);
  float rs = rsqrtf(q * (1.0f / DIM_) + 1e-5f);
  float y[6];
#pragma unroll
  for (int j = 0; j < 6; ++j)
    y[j] = (v[j] - mu) * rs * w[lane + 64 * j] + b[lane + 64 * j];
  int wdw = tok >> 6, t = tok & 63;
  int rank = win_rank[wdw];
  if (rank < 0) {
#pragma unroll
    for (int j = 0; j < 6; ++j) out[(size_t)tok * DIM_ + lane + 64 * j] = y[j];
  } else {
    int jdx = (rank << 6) + t;
    int i = inv_ip[jdx];
#pragma unroll
    for (int j = 0; j < 6; ++j) xp[(size_t)i * DIM_ + lane + 64 * j] = f2bf(y[j]);
    if ((bitmap[jdx >> 5] >> (jdx & 31)) & 1) {
#pragma unroll
      for (int j = 0; j < 6; ++j) out[(size_t)tok * DIM_ + lane + 64 * j] = y[j];
    }
  }
}

// ---------------- LN2 ----------------
__global__ __launch_bounds__(256) void ln2_k(const short* __restrict__ h,
                                             const float* __restrict__ w,
                                             const float* __restrict__ b,
                                             short* __restrict__ outln) {
  int lane = threadIdx.x & 63;
  int tok = (blockIdx.x << 2) + (threadIdx.x >> 6);
  const short* xr = h + (size_t)tok * DIM_;
  float v[6]; float s = 0.f;
#pragma unroll
  for (int j = 0; j < 6; ++j) { v[j] = bf2f(xr[lane + 64 * j]); s += v[j]; }
#pragma unroll
  for (int m = 1; m < 64; m <<= 1) s += __shfl_xor(s, m, 64);
  float mu = s * (1.0f / DIM_);
  float q = 0.f;
#pragma unroll
  for (int j = 0; j < 6; ++j) { float d = v[j] - mu; q += d * d; }
#pragma unroll
  for (int m = 1; m < 64; m <<= 1) q += __shfl_xor(q, m, 64);
  float rs = rsqrtf(q * (1.0f / DIM_) + 1e-5f);
#pragma unroll
  for (int j = 0; j < 6; ++j) {
    float y = (v[j] - mu) * rs * w[lane + 64 * j] + b[lane + 64 * j];
    outln[(size_t)tok * DIM_ + lane + 64 * j] = f2bf(y);
  }
}

// ---------------- GEMM (round-1 structure): C = A * B^T ----------------
// 128x128 tile, single-buffer LDS, __syncthreads pipeline, XCD-chunk swizzle.
// EPI 0: +bias -> bf16 (ld N)   (QKV)
// EPI 1: +bias +add_bf -> bf16  (proj + residual -> h)
template <int EPI>
__global__ __launch_bounds__(256) void gemm_k(const short* __restrict__ A,
                                              const short* __restrict__ B,
                                              const float* __restrict__ bias,
                                              int K, int N, int nx,
                                              short* __restrict__ Cb,
                                              const short* __restrict__ add_bf) {
  const int nwg = gridDim.x;
  const int q8 = nwg >> 3;
  const int wg = (blockIdx.x & 7) * q8 + (blockIdx.x >> 3);
  const int ntile = wg % nx, mtile = wg / nx;
  const int tid = threadIdx.x, wid = tid >> 6, lane = tid & 63;
  const int fq = lane >> 4, fr = lane & 15;
  const int wr = wid >> 1, wc = wid & 1;
  __shared__ __align__(16) short lA[128 * 64];
  __shared__ __align__(16) short lB[128 * 64];
  const int row0 = mtile * 128, col0 = ntile * 128;
  float bs[4];
#pragma unroll
  for (int nt = 0; nt < 4; ++nt) bs[nt] = bias[col0 + wc * 64 + nt * 16 + fr];
  f32x4 acc[4][4];
#pragma unroll
  for (int a = 0; a < 4; ++a)
#pragma unroll
    for (int c = 0; c < 4; ++c) acc[a][c] = (f32x4){0.f, 0.f, 0.f, 0.f};
  const int nkt = K >> 6;
  for (int kt = 0; kt < nkt; ++kt) {
    const int k0 = kt << 6;
#pragma unroll
    for (int i = 0; i < 4; ++i) {
      int cb = ((i * 4 + wid) << 6) + lane;
      int r = cb >> 3, c8 = cb & 7;
      int s8 = c8 ^ (r & 7);
      gload16(A + (size_t)(row0 + r) * K + k0 + s8 * 8,
              (char*)lA + (size_t)(i * 4 + wid) * 1024);
      gload16(B + (size_t)(col0 + r) * K + k0 + s8 * 8,
              (char*)lB + (size_t)(i * 4 + wid) * 1024);
    }
    WAITSYNC();
#pragma unroll
    for (int ks = 0; ks < 2; ++ks) {
      bf16x8 af[4], bfr[4];
#pragma unroll
      for (int mt = 0; mt < 4; ++mt) {
        int r = wr * 64 + mt * 16 + fr;
        af[mt] = *(const bf16x8*)&lA[r * 64 + ((ks * 4 + fq) ^ (r & 7)) * 8];
      }
#pragma unroll
      for (int nt = 0; nt < 4; ++nt) {
        int r = wc * 64 + nt * 16 + fr;
        bfr[nt] = *(const bf16x8*)&lB[r * 64 + ((ks * 4 + fq) ^ (r & 7)) * 8];
      }
#pragma unroll
      for (int mt = 0; mt < 4; ++mt)
#pragma unroll
        for (int nt = 0; nt < 4; ++nt)
          acc[mt][nt] = mfma16(af[mt], bfr[nt], acc[mt][nt]);
    }
    WAITSYNC();
  }
#pragma unroll
  for (int mt = 0; mt < 4; ++mt) {
#pragma unroll
    for (int jj = 0; jj < 4; ++jj) {
      int r = row0 + wr * 64 + mt * 16 + fq * 4 + jj;
#pragma unroll
      for (int nt = 0; nt < 4; ++nt) {
        int gcol = col0 + wc * 64 + nt * 16 + fr;
        float v = acc[mt][nt][jj] + bs[nt];
        if (EPI == 0) {
          Cb[(size_t)r * N + gcol] = f2bf(v);
        } else {
          v += bf2f(add_bf[(size_t)r * DIM_ + gcol]);
          Cb[(size_t)r * DIM_ + gcol] = f2bf(v);
        }
      }
    }
  }
}

// ---------------- fused MLP: out = scatter(gelu(A@W1^T+b1)@W2^T + b2 + hres) --
// Block = 64 rows, 512 threads (8 waves). lA staged once. 12 chunks of 128
// MLP cols. Strict distance-1 double-buffer for W1/W2 slices; EVERY barrier
// is an explicit full drain (WAITSYNC), so no load is ever in flight across
// a barrier and every prefetch targets the buffer not being read.
__global__ __launch_bounds__(512) void mlp_k(const short* __restrict__ A,
                                             const short* __restrict__ W1,
                                             const float* __restrict__ b1,
                                             const short* __restrict__ W2,
                                             const float* __restrict__ b2,
                                             const short* __restrict__ hres,
                                             const int* __restrict__ rowmap,
                                             float* __restrict__ outf) {
  __shared__ __align__(16) short lA[64 * 384];       // 48 KB
  __shared__ __align__(16) short tL[64 * 128];       // 16 KB
  __shared__ __align__(16) short lW1[2][128 * 64];   // 32 KB
  __shared__ __align__(16) short lW2[2][192 * 64];   // 48 KB
  const int tid = threadIdx.x, wid = tid >> 6, lane = tid & 63;
  const int fq = lane >> 4, fr = lane & 15;
  const int wrt = wid >> 2, wct = wid & 3;  // 2 (row) x 4 (col) wave grid
  const int row0 = blockIdx.x * 64;

  auto stageA = [&]() {
#pragma unroll
    for (int i = 0; i < 6; ++i) {
      int g = i * 512 + tid;
      int r = g / 48, c8 = g % 48;
      int s8 = c8 ^ (r & 7);
      gload16(A + (size_t)(row0 + r) * 384 + s8 * 8,
              (char*)lA + (size_t)(i * 512 + wid * 64) * 16);
    }
  };
  auto stageW1 = [&](int buf, int c, int kt) {
#pragma unroll
    for (int i = 0; i < 2; ++i) {
      int g = i * 512 + tid;
      int r = g >> 3, c8 = g & 7;
      int s8 = c8 ^ (r & 7);
      gload16(W1 + (size_t)(c * 128 + r) * 384 + kt * 64 + s8 * 8,
              (char*)lW1[buf] + (size_t)(i * 512 + wid * 64) * 16);
    }
  };
  auto stageW2 = [&](int buf, int c, int s) {  // s: kh = s>>1, oh = s&1
    const int kh = s >> 1, oh = s & 1;
#pragma unroll
    for (int i = 0; i < 3; ++i) {
      int g = i * 512 + tid;
      int r = g >> 3, c8 = g & 7;
      int s8 = c8 ^ (r & 7);
      gload16(W2 + (size_t)(oh * 192 + r) * 1536 + c * 128 + kh * 64 + s8 * 8,
              (char*)lW2[buf] + (size_t)(i * 512 + wid * 64) * 16);
    }
  };

  f32x4 acc[2][6];
#pragma unroll
  for (int a = 0; a < 2; ++a)
#pragma unroll
    for (int c = 0; c < 6; ++c) acc[a][c] = (f32x4){0.f, 0.f, 0.f, 0.f};

  stageA();
  stageW1(0, 0, 0);
  WAITSYNC();

  for (int c = 0; c < 12; ++c) {
    f32x4 acc_t[2][2];
#pragma unroll
    for (int a = 0; a < 2; ++a)
#pragma unroll
      for (int n = 0; n < 2; ++n) acc_t[a][n] = (f32x4){0.f, 0.f, 0.f, 0.f};
    // ---- t = A @ W1_c^T : 6 k-steps of 64, distance-1 dbuf ----
    for (int kt = 0; kt < 6; ++kt) {
      if (kt < 5) stageW1((kt + 1) & 1, c, kt + 1);  // other buffer
      else        stageW2(0, c, 0);                  // FC2 slice0 prefetch
      const int buf = kt & 1;
#pragma unroll
      for (int ks = 0; ks < 2; ++ks) {
        bf16x8 a2[2], br[2];
#pragma unroll
        for (int mt = 0; mt < 2; ++mt) {
          int r = wrt * 32 + mt * 16 + fr;
          a2[mt] = *(const bf16x8*)&lA[(r * 48 + ((kt * 8 + ks * 4 + fq) ^ (r & 7))) * 8];
        }
#pragma unroll
        for (int nt = 0; nt < 2; ++nt) {
          int r = wct * 32 + nt * 16 + fr;
          br[nt] = *(const bf16x8*)&lW1[buf][(r * 8 + ((ks * 4 + fq) ^ (r & 7))) * 8];
        }
#pragma unroll
        for (int mt = 0; mt < 2; ++mt)
#pragma unroll
          for (int nt = 0; nt < 2; ++nt)
            acc_t[mt][nt] = mfma16(a2[mt], br[nt], acc_t[mt][nt]);
      }
      WAITSYNC();
    }
    // ---- gelu + bias, write t (swizzled) ----
    float b1v[2];
#pragma unroll
    for (int nt = 0; nt < 2; ++nt) b1v[nt] = b1[c * 128 + wct * 32 + nt * 16 + fr];
#pragma unroll
    for (int mt = 0; mt < 2; ++mt)
#pragma unroll
      for (int nt = 0; nt < 2; ++nt)
#pragma unroll
        for (int jj = 0; jj < 4; ++jj) {
          int row = wrt * 32 + mt * 16 + fq * 4 + jj;
          int col = wct * 32 + nt * 16 + fr;
          float v = acc_t[mt][nt][jj] + b1v[nt];
          float u = v * (0.79788456f + 0.03567741f * v * v);
          float gl = v * __builtin_amdgcn_rcpf(1.0f + __expf(-2.0f * u));
          int gcol = col >> 3;
          tL[row * 128 + ((gcol ^ (row & 7)) << 3) + (col & 7)] = f2bf(gl);
        }
    WAITSYNC();
    // ---- out += t @ W2_c^T : slices 0..3 (kh = s>>1, oh = s&1), dist-1 dbuf --
#pragma unroll
    for (int s = 0; s < 4; ++s) {
      if (s < 3)       stageW2((s + 1) & 1, c, s + 1);  // other buffer
      else if (c < 11) stageW1(0, c + 1, 0);            // next chunk W1 k0
      const int kh = s >> 1, oh = s & 1, buf = s & 1;
#pragma unroll
      for (int ks = 0; ks < 2; ++ks) {
        bf16x8 a2[2], br[3];
#pragma unroll
        for (int mt = 0; mt < 2; ++mt) {
          int r = wrt * 32 + mt * 16 + fr;
          a2[mt] = *(const bf16x8*)&tL[(r * 16 + ((kh * 8 + ks * 4 + fq) ^ (r & 7))) * 8];
        }
#pragma unroll
        for (int nt = 0; nt < 3; ++nt) {
          int r = wct * 48 + nt * 16 + fr;
          br[nt] = *(const bf16x8*)&lW2[buf][(r * 8 + ((ks * 4 + fq) ^ (r & 7))) * 8];
        }
#pragma unroll
        for (int mt = 0; mt < 2; ++mt)
#pragma unroll
          for (int nt = 0; nt < 3; ++nt)
            acc[mt][oh * 3 + nt] = mfma16(a2[mt], br[nt], acc[mt][oh * 3 + nt]);
      }
      WAITSYNC();
    }
  }
  // ---- epilogue: bias + residual + scatter ----
  float b2v[6];
#pragma unroll
  for (int oh = 0; oh < 2; ++oh)
#pragma unroll
    for (int nt = 0; nt < 3; ++nt)
      b2v[oh * 3 + nt] = b2[oh * 192 + wct * 48 + nt * 16 + fr];
#pragma unroll
  for (int mt = 0; mt < 2; ++mt)
#pragma unroll
    for (int jj = 0; jj < 4; ++jj) {
      int r = row0 + wrt * 32 + mt * 16 + fq * 4 + jj;
      int dmap = rowmap[r];
#pragma unroll
      for (int oh = 0; oh < 2; ++oh)
#pragma unroll
        for (int nt = 0; nt < 3; ++nt) {
          int col = oh * 192 + wct * 48 + nt * 16 + fr;
          float v = acc[mt][oh * 3 + nt][jj] + b2v[oh * 3 + nt] +
                    bf2f(hres[(size_t)r * DIM_ + col]);
          if (dmap >= 0) outf[(size_t)dmap * DIM_ + col] = v;
        }
    }
}

// ---------------- attention ----------------
__global__ __launch_bounds__(256) void attn_k(const short* __restrict__ qkv,
                                              const unsigned* __restrict__ bitmap,
                                              const int* __restrict__ ip,
                                              short* __restrict__ o) {
  const int m = blockIdx.x;
  const int wid = threadIdx.x >> 6, lane = threadIdx.x & 63;
  const int fq = lane >> 4, fr = lane & 15;
  __shared__ __align__(16) short P[4][64 * 72];
  __shared__ __align__(16) short Vt[4][32 * 72];
  __shared__ unsigned char flags[64];
  if (threadIdx.x < 64) {
    int j = ip[m * 64 + threadIdx.x];
    flags[threadIdx.x] = (unsigned char)((bitmap[j >> 5] >> (j & 31)) & 1);
  }
  __syncthreads();
  const float scale = 0.17677669529663687f;
  int msk[4];
#pragma unroll
  for (int nt = 0; nt < 4; ++nt) msk[nt] = flags[nt * 16 + fr];

  for (int hh = 0; hh < 3; ++hh) {
    int h = wid * 3 + hh;
    const short* base = qkv + (size_t)m * 64 * QKVD_ + h * 96;
    f32x4 sacc[4][4];
#pragma unroll
    for (int a = 0; a < 4; ++a)
#pragma unroll
      for (int c = 0; c < 4; ++c) sacc[a][c] = (f32x4){0.f, 0.f, 0.f, 0.f};
    bf16x8 qa[4], kb[4];
#pragma unroll
    for (int mt = 0; mt < 4; ++mt)
      qa[mt] = *(const bf16x8*)(base + (size_t)(mt * 16 + fr) * QKVD_ + fq * 8);
#pragma unroll
    for (int nt = 0; nt < 4; ++nt)
      kb[nt] = *(const bf16x8*)(base + (size_t)(nt * 16 + fr) * QKVD_ + 32 + fq * 8);
#pragma unroll
    for (int mt = 0; mt < 4; ++mt)
#pragma unroll
      for (int nt = 0; nt < 4; ++nt)
        sacc[mt][nt] = mfma16(qa[mt], kb[nt], sacc[mt][nt]);
#pragma unroll
    for (int c = 0; c < 4; ++c) {
      bf16x8 vv = *(const bf16x8*)(base + (size_t)lane * QKVD_ + 64 + c * 8);
#pragma unroll
      for (int e = 0; e < 8; ++e) Vt[wid][(c * 8 + e) * 72 + lane] = vv[e];
    }
#pragma unroll
    for (int mt = 0; mt < 4; ++mt)
#pragma unroll
      for (int nt = 0; nt < 4; ++nt) {
        f32x4 sv = sacc[mt][nt];
#pragma unroll
        for (int jj = 0; jj < 4; ++jj)
          sv[jj] = msk[nt] ? -10000.0f : sv[jj] * scale;
        sacc[mt][nt] = sv;
      }
#pragma unroll
    for (int mt = 0; mt < 4; ++mt) {
#pragma unroll
      for (int jj = 0; jj < 4; ++jj) {
        float mx = sacc[mt][0][jj];
#pragma unroll
        for (int nt = 1; nt < 4; ++nt) mx = fmaxf(mx, sacc[mt][nt][jj]);
#pragma unroll
        for (int mm = 1; mm < 16; mm <<= 1) mx = fmaxf(mx, __shfl_xor(mx, mm, 64));
        float sm = 0.f;
        float p[4];
#pragma unroll
        for (int nt = 0; nt < 4; ++nt) {
          p[nt] = __expf(sacc[mt][nt][jj] - mx);
          sm += p[nt];
        }
#pragma unroll
        for (int mm = 1; mm < 16; mm <<= 1) sm += __shfl_xor(sm, mm, 64);
        float inv = 1.0f / sm;
        int rowb = (mt * 16 + fq * 4 + jj) * 72;
#pragma unroll
        for (int nt = 0; nt < 4; ++nt)
          P[wid][rowb + nt * 16 + fr] = f2bf(p[nt] * inv);
      }
    }
    f32x4 oacc[4][2];
#pragma unroll
    for (int a = 0; a < 4; ++a)
#pragma unroll
      for (int c = 0; c < 2; ++c) oacc[a][c] = (f32x4){0.f, 0.f, 0.f, 0.f};
#pragma unroll
    for (int ks = 0; ks < 2; ++ks) {
      bf16x8 pa[4], vb[2];
#pragma unroll
      for (int mt = 0; mt < 4; ++mt)
        pa[mt] = *(const bf16x8*)&P[wid][(mt * 16 + fr) * 72 + ks * 32 + fq * 8];
#pragma unroll
      for (int nd = 0; nd < 2; ++nd)
        vb[nd] = *(const bf16x8*)&Vt[wid][(nd * 16 + fr) * 72 + ks * 32 + fq * 8];
#pragma unroll
      for (int mt = 0; mt < 4; ++mt)
#pragma unroll
        for (int nd = 0; nd < 2; ++nd)
          oacc[mt][nd] = mfma16(pa[mt], vb[nd], oacc[mt][nd]);
    }
#pragma unroll
    for (int mt = 0; mt < 4; ++mt)
#pragma unroll
      for (int nd = 0; nd < 2; ++nd)
#pragma unroll
        for (int jj = 0; jj < 4; ++jj)
          o[(size_t)(m * 64 + mt * 16 + fq * 4 + jj) * DIM_ + h * 32 + nd * 16 + fr] =
              f2bf(oacc[mt][nd][jj]);
  }
}

// ---------------- launch ----------------
extern "C" void kernel_launch(void* const* d_in, const int* in_sizes, int n_in,
                              void* d_out, int out_size, void* d_ws, size_t ws_size,
                              hipStream_t stream) {
  const float* x = (const float*)d_in[0];
  const int* iw = (const int*)d_in[1];
  const int* ip = (const int*)d_in[2];
  const int* blk = (const int*)d_in[3];
  const float* ln1w = (const float*)d_in[6];
  const float* ln1b = (const float*)d_in[7];
  const float* qkvw = (const float*)d_in[8];
  const float* qkvb = (const float*)d_in[9];
  const float* projw = (const float*)d_in[10];
  const float* projb = (const float*)d_in[11];
  const float* ln2w = (const float*)d_in[12];
  const float* ln2b = (const float*)d_in[13];
  const float* fc1w = (const float*)d_in[14];
  const float* fc1b = (const float*)d_in[15];
  const float* fc2w = (const float*)d_in[16];
  const float* fc2b = (const float*)d_in[17];
  float* out = (float*)d_out;

  char* ws = (char*)d_ws;
  short* w_all = (short*)ws;                 // 1,769,472 bf16
  short* w_qkv = w_all;
  short* w_proj = w_all + 442368;
  short* w_fc1 = w_all + 589824;
  short* w_fc2 = w_all + 1179648;
  int* inv_ip = (int*)(ws + 3538944);
  int* rowmap = inv_ip + NTOK_;
  int* win_rank = rowmap + NTOK_;
  unsigned* bitmap = (unsigned*)(win_rank + NW_);
  short* xp = (short*)(ws + 4349952);                        // 75.5 MB (also ln2 out)
  short* qkv_g = (short*)(ws + 4349952 + 75497472);          // 226.5 MB (qkv)
  short* obuf = (short*)(ws + 381837312);                    // 75.5 MB
  short* hbuf = (short*)(ws + 457334784);                    // 75.5 MB
  short* ln2buf = xp;
  (void)in_sizes; (void)n_in; (void)out_size; (void)ws_size;

  mapA_k<<<12, 256, 0, stream>>>(win_rank, bitmap);
  mapB_k<<<39, 256, 0, stream>>>(iw, blk, win_rank, bitmap);
  mapC_k<<<NTOK_ / 256, 256, 0, stream>>>(ip, iw, bitmap, inv_ip, rowmap);
  wconv_k<<<6912, 256, 0, stream>>>(qkvw, projw, fc1w, fc2w, w_all);
  ln1_k<<<(NW_ * 64) / 4, 256, 0, stream>>>(x, ln1w, ln1b, win_rank, inv_ip, bitmap,
                                            out, xp);
  gemm_k<0><<<768 * 9, 256, 0, stream>>>(xp, w_qkv, qkvb, 384, QKVD_, 9, qkv_g,
                                         nullptr);
  attn_k<<<WACT_, 256, 0, stream>>>(qkv_g, bitmap, ip, obuf);
  gemm_k<1><<<768 * 3, 256, 0, stream>>>(obuf, w_proj, projb, 384, DIM_, 3, hbuf,
                                         xp);
  ln2_k<<<NTOK_ / 4, 256, 0, stream>>>(hbuf, ln2w, ln2b, ln2buf);
  mlp_k<<<NTOK_ / 64, 512, 0, stream>>>(ln2buf, w_fc1, fc1b, w_fc2, fc2b, hbuf,
                                        rowmap, out);
}

// Round 7
// 900.740 us; speedup vs baseline: 1.2807x; 1.1997x over previous
//
#include <hip/hip_runtime.h>
#include <hip/hip_bf16.h>

typedef __attribute__((ext_vector_type(8))) short bf16x8;
typedef __attribute__((ext_vector_type(4))) float f32x4;

#define NW_   3072
#define WACT_ 1536
#define NTOK_ 98304
#define NBLK_ 9830
#define DIM_  384
#define QKVD_ 1152
#define MLPD_ 1536

__device__ __forceinline__ float bf2f(short s) {
  union { unsigned u; float f; } c;
  c.u = ((unsigned)(unsigned short)s) << 16;
  return c.f;
}
__device__ __forceinline__ short f2bf(float f) {
  union { float f; unsigned u; } c; c.f = f;
  unsigned lsb = (c.u >> 16) & 1u;
  c.u += 0x7fffu + lsb;
  return (short)(c.u >> 16);
}

__device__ __forceinline__ f32x4 mfma16(bf16x8 a, bf16x8 b, f32x4 c) {
  return __builtin_amdgcn_mfma_f32_16x16x32_bf16(a, b, c, 0, 0, 0);
}

__device__ __forceinline__ void gload16(const void* g, void* l) {
  __builtin_amdgcn_global_load_lds(
      (const __attribute__((address_space(1))) unsigned*)g,
      (__attribute__((address_space(3))) unsigned*)l, 16, 0, 0);
}

// ---------------- map kernels ----------------
__global__ __launch_bounds__(256) void mapA_k(int* win_rank, unsigned* bitmap) {
  int t = blockIdx.x * 256 + threadIdx.x;
  if (t < NW_) { win_rank[t] = -1; bitmap[t] = 0u; }
}

__global__ __launch_bounds__(256) void mapB_k(const int* __restrict__ iw,
                                              const int* __restrict__ blk,
                                              int* win_rank, unsigned* bitmap) {
  int t = blockIdx.x * 256 + threadIdx.x;
  if (t < WACT_) win_rank[iw[t]] = t;
  if (t < NBLK_) { int j = blk[t]; atomicOr(&bitmap[j >> 5], 1u << (j & 31)); }
}

__global__ __launch_bounds__(256) void mapC_k(const int* __restrict__ ip,
                                              const int* __restrict__ iw,
                                              const unsigned* __restrict__ bitmap,
                                              int* inv_ip, int* rowmap) {
  int i = blockIdx.x * 256 + threadIdx.x;
  if (i < NTOK_) {
    int j = ip[i];
    inv_ip[j] = i;
    int blocked = (bitmap[j >> 5] >> (j & 31)) & 1;
    rowmap[i] = blocked ? -1 : (iw[j >> 6] * 64 + (j & 63));
  }
}

// ---------------- weight conversion ----------------
__global__ __launch_bounds__(256) void wconv_k(const float* __restrict__ qkvw,
                                               const float* __restrict__ projw,
                                               const float* __restrict__ fc1w,
                                               const float* __restrict__ fc2w,
                                               short* __restrict__ dst) {
  int i = blockIdx.x * 256 + threadIdx.x;  // total 1,769,472
  float v;
  if (i < 442368) v = qkvw[i];
  else if (i < 589824) v = projw[i - 442368];
  else if (i < 1179648) v = fc1w[i - 589824];
  else v = fc2w[i - 1179648];
  dst[i] = f2bf(v);
}

// ---------------- LN1 + gather/permute ----------------
__global__ __launch_bounds__(256) void ln1_k(const float* __restrict__ x,
                                             const float* __restrict__ w,
                                             const float* __restrict__ b,
                                             const int* __restrict__ win_rank,
                                             const int* __restrict__ inv_ip,
                                             const unsigned* __restrict__ bitmap,
                                             float* __restrict__ out,
                                             short* __restrict__ xp) {
  int lane = threadIdx.x & 63;
  int tok = (blockIdx.x << 2) + (threadIdx.x >> 6);
  const float* xr = x + (size_t)tok * DIM_;
  float v[6]; float s = 0.f;
#pragma unroll
  for (int j = 0; j < 6; ++j) { v[j] = xr[lane + 64 * j]; s += v[j]; }
#pragma unroll
  for (int m = 1; m < 64; m <<= 1) s += __shfl_xor(s, m, 64);
  float mu = s * (1.0f / DIM_);
  float q = 0.f;
#pragma unroll
  for (int j = 0; j < 6; ++j) { float d = v[j] - mu; q += d * d; }
#pragma unroll
  for (int m = 1; m < 64; m <<= 1) q += __shfl_xor(q, m, 64);
  float rs = rsqrtf(q * (1.0f / DIM_) + 1e-5f);
  float y[6];
#pragma unroll
  for (int j = 0; j < 6; ++j)
    y[j] = (v[j] - mu) * rs * w[lane + 64 * j] + b[lane + 64 * j];
  int wdw = tok >> 6, t = tok & 63;
  int rank = win_rank[wdw];
  if (rank < 0) {
#pragma unroll
    for (int j = 0; j < 6; ++j) out[(size_t)tok * DIM_ + lane + 64 * j] = y[j];
  } else {
    int jdx = (rank << 6) + t;
    int i = inv_ip[jdx];
#pragma unroll
    for (int j = 0; j < 6; ++j) xp[(size_t)i * DIM_ + lane + 64 * j] = f2bf(y[j]);
    if ((bitmap[jdx >> 5] >> (jdx & 31)) & 1) {
#pragma unroll
      for (int j = 0; j < 6; ++j) out[(size_t)tok * DIM_ + lane + 64 * j] = y[j];
    }
  }
}

// ---------------- LN2 ----------------
__global__ __launch_bounds__(256) void ln2_k(const short* __restrict__ h,
                                             const float* __restrict__ w,
                                             const float* __restrict__ b,
                                             short* __restrict__ outln) {
  int lane = threadIdx.x & 63;
  int tok = (blockIdx.x << 2) + (threadIdx.x >> 6);
  const short* xr = h + (size_t)tok * DIM_;
  float v[6]; float s = 0.f;
#pragma unroll
  for (int j = 0; j < 6; ++j) { v[j] = bf2f(xr[lane + 64 * j]); s += v[j]; }
#pragma unroll
  for (int m = 1; m < 64; m <<= 1) s += __shfl_xor(s, m, 64);
  float mu = s * (1.0f / DIM_);
  float q = 0.f;
#pragma unroll
  for (int j = 0; j < 6; ++j) { float d = v[j] - mu; q += d * d; }
#pragma unroll
  for (int m = 1; m < 64; m <<= 1) q += __shfl_xor(q, m, 64);
  float rs = rsqrtf(q * (1.0f / DIM_) + 1e-5f);
#pragma unroll
  for (int j = 0; j < 6; ++j) {
    float y = (v[j] - mu) * rs * w[lane + 64 * j] + b[lane + 64 * j];
    outln[(size_t)tok * DIM_ + lane + 64 * j] = f2bf(y);
  }
}

// ---------------- GEMM (round-1 structure): C = A * B^T ----------------
// 128x128 tile, single-buffer LDS (32 KB -> ~5 blocks/CU), __syncthreads
// pipeline, flat-grid XCD-chunk swizzle, bias hoisted to regs.
// EPI 0: +bias -> bf16 (ld N)        (QKV)
// EPI 1: +bias +add_bf -> bf16       (proj + residual -> h)
// EPI 2: +bias, fast gelu -> bf16    (fc1)
// EPI 3: +bias +add_bf, scatter fp32 (fc2 + residual -> out)
template <int EPI>
__global__ __launch_bounds__(256) void gemm_k(const short* __restrict__ A,
                                              const short* __restrict__ B,
                                              const float* __restrict__ bias,
                                              int K, int N, int nx,
                                              short* __restrict__ Cb,
                                              const short* __restrict__ add_bf,
                                              const int* __restrict__ rowmap,
                                              float* __restrict__ outf) {
  const int nwg = gridDim.x;
  const int q8 = nwg >> 3;
  const int wg = (blockIdx.x & 7) * q8 + (blockIdx.x >> 3);
  const int ntile = wg % nx, mtile = wg / nx;
  const int tid = threadIdx.x, wid = tid >> 6, lane = tid & 63;
  const int fq = lane >> 4, fr = lane & 15;
  const int wr = wid >> 1, wc = wid & 1;
  __shared__ __align__(16) short lA[128 * 64];
  __shared__ __align__(16) short lB[128 * 64];
  const int row0 = mtile * 128, col0 = ntile * 128;
  float bs[4];
#pragma unroll
  for (int nt = 0; nt < 4; ++nt) bs[nt] = bias[col0 + wc * 64 + nt * 16 + fr];
  f32x4 acc[4][4];
#pragma unroll
  for (int a = 0; a < 4; ++a)
#pragma unroll
    for (int c = 0; c < 4; ++c) acc[a][c] = (f32x4){0.f, 0.f, 0.f, 0.f};
  const int nkt = K >> 6;
  for (int kt = 0; kt < nkt; ++kt) {
    const int k0 = kt << 6;
#pragma unroll
    for (int i = 0; i < 4; ++i) {
      int cb = ((i * 4 + wid) << 6) + lane;
      int r = cb >> 3, c8 = cb & 7;
      int s8 = c8 ^ (r & 7);
      gload16(A + (size_t)(row0 + r) * K + k0 + s8 * 8,
              (char*)lA + (size_t)(i * 4 + wid) * 1024);
      gload16(B + (size_t)(col0 + r) * K + k0 + s8 * 8,
              (char*)lB + (size_t)(i * 4 + wid) * 1024);
    }
    __syncthreads();
#pragma unroll
    for (int ks = 0; ks < 2; ++ks) {
      bf16x8 af[4], bfr[4];
#pragma unroll
      for (int mt = 0; mt < 4; ++mt) {
        int r = wr * 64 + mt * 16 + fr;
        af[mt] = *(const bf16x8*)&lA[r * 64 + ((ks * 4 + fq) ^ (r & 7)) * 8];
      }
#pragma unroll
      for (int nt = 0; nt < 4; ++nt) {
        int r = wc * 64 + nt * 16 + fr;
        bfr[nt] = *(const bf16x8*)&lB[r * 64 + ((ks * 4 + fq) ^ (r & 7)) * 8];
      }
#pragma unroll
      for (int mt = 0; mt < 4; ++mt)
#pragma unroll
        for (int nt = 0; nt < 4; ++nt)
          acc[mt][nt] = mfma16(af[mt], bfr[nt], acc[mt][nt]);
    }
    __syncthreads();
  }
#pragma unroll
  for (int mt = 0; mt < 4; ++mt) {
#pragma unroll
    for (int jj = 0; jj < 4; ++jj) {
      int r = row0 + wr * 64 + mt * 16 + fq * 4 + jj;
      int dmap = 0;
      if (EPI == 3) dmap = rowmap[r];
#pragma unroll
      for (int nt = 0; nt < 4; ++nt) {
        int gcol = col0 + wc * 64 + nt * 16 + fr;
        float v = acc[mt][nt][jj] + bs[nt];
        if (EPI == 0) {
          Cb[(size_t)r * N + gcol] = f2bf(v);
        } else if (EPI == 1) {
          v += bf2f(add_bf[(size_t)r * DIM_ + gcol]);
          Cb[(size_t)r * DIM_ + gcol] = f2bf(v);
        } else if (EPI == 2) {
          // gelu(x) ~= x * sigmoid(2u), u = 0.79788456*(x + 0.044715 x^3)
          float u = v * (0.79788456f + 0.03567741f * v * v);
          float g = v * __builtin_amdgcn_rcpf(1.0f + __expf(-2.0f * u));
          Cb[(size_t)r * MLPD_ + gcol] = f2bf(g);
        } else {
          v += bf2f(add_bf[(size_t)r * DIM_ + gcol]);
          if (dmap >= 0) outf[(size_t)dmap * DIM_ + gcol] = v;
        }
      }
    }
  }
}

// ---------------- attention ----------------
__global__ __launch_bounds__(256) void attn_k(const short* __restrict__ qkv,
                                              const unsigned* __restrict__ bitmap,
                                              const int* __restrict__ ip,
                                              short* __restrict__ o) {
  const int m = blockIdx.x;
  const int wid = threadIdx.x >> 6, lane = threadIdx.x & 63;
  const int fq = lane >> 4, fr = lane & 15;
  __shared__ __align__(16) short P[4][64 * 72];
  __shared__ __align__(16) short Vt[4][32 * 72];
  __shared__ unsigned char flags[64];
  if (threadIdx.x < 64) {
    int j = ip[m * 64 + threadIdx.x];
    flags[threadIdx.x] = (unsigned char)((bitmap[j >> 5] >> (j & 31)) & 1);
  }
  __syncthreads();
  const float scale = 0.17677669529663687f;
  int msk[4];
#pragma unroll
  for (int nt = 0; nt < 4; ++nt) msk[nt] = flags[nt * 16 + fr];

  for (int hh = 0; hh < 3; ++hh) {
    int h = wid * 3 + hh;
    const short* base = qkv + (size_t)m * 64 * QKVD_ + h * 96;
    f32x4 sacc[4][4];
#pragma unroll
    for (int a = 0; a < 4; ++a)
#pragma unroll
      for (int c = 0; c < 4; ++c) sacc[a][c] = (f32x4){0.f, 0.f, 0.f, 0.f};
    bf16x8 qa[4], kb[4];
#pragma unroll
    for (int mt = 0; mt < 4; ++mt)
      qa[mt] = *(const bf16x8*)(base + (size_t)(mt * 16 + fr) * QKVD_ + fq * 8);
#pragma unroll
    for (int nt = 0; nt < 4; ++nt)
      kb[nt] = *(const bf16x8*)(base + (size_t)(nt * 16 + fr) * QKVD_ + 32 + fq * 8);
#pragma unroll
    for (int mt = 0; mt < 4; ++mt)
#pragma unroll
      for (int nt = 0; nt < 4; ++nt)
        sacc[mt][nt] = mfma16(qa[mt], kb[nt], sacc[mt][nt]);
#pragma unroll
    for (int c = 0; c < 4; ++c) {
      bf16x8 vv = *(const bf16x8*)(base + (size_t)lane * QKVD_ + 64 + c * 8);
#pragma unroll
      for (int e = 0; e < 8; ++e) Vt[wid][(c * 8 + e) * 72 + lane] = vv[e];
    }
#pragma unroll
    for (int mt = 0; mt < 4; ++mt)
#pragma unroll
      for (int nt = 0; nt < 4; ++nt) {
        f32x4 sv = sacc[mt][nt];
#pragma unroll
        for (int jj = 0; jj < 4; ++jj)
          sv[jj] = msk[nt] ? -10000.0f : sv[jj] * scale;
        sacc[mt][nt] = sv;
      }
#pragma unroll
    for (int mt = 0; mt < 4; ++mt) {
#pragma unroll
      for (int jj = 0; jj < 4; ++jj) {
        float mx = sacc[mt][0][jj];
#pragma unroll
        for (int nt = 1; nt < 4; ++nt) mx = fmaxf(mx, sacc[mt][nt][jj]);
#pragma unroll
        for (int mm = 1; mm < 16; mm <<= 1) mx = fmaxf(mx, __shfl_xor(mx, mm, 64));
        float sm = 0.f;
        float p[4];
#pragma unroll
        for (int nt = 0; nt < 4; ++nt) {
          p[nt] = __expf(sacc[mt][nt][jj] - mx);
          sm += p[nt];
        }
#pragma unroll
        for (int mm = 1; mm < 16; mm <<= 1) sm += __shfl_xor(sm, mm, 64);
        float inv = 1.0f / sm;
        int rowb = (mt * 16 + fq * 4 + jj) * 72;
#pragma unroll
        for (int nt = 0; nt < 4; ++nt)
          P[wid][rowb + nt * 16 + fr] = f2bf(p[nt] * inv);
      }
    }
    f32x4 oacc[4][2];
#pragma unroll
    for (int a = 0; a < 4; ++a)
#pragma unroll
      for (int c = 0; c < 2; ++c) oacc[a][c] = (f32x4){0.f, 0.f, 0.f, 0.f};
#pragma unroll
    for (int ks = 0; ks < 2; ++ks) {
      bf16x8 pa[4], vb[2];
#pragma unroll
      for (int mt = 0; mt < 4; ++mt)
        pa[mt] = *(const bf16x8*)&P[wid][(mt * 16 + fr) * 72 + ks * 32 + fq * 8];
#pragma unroll
      for (int nd = 0; nd < 2; ++nd)
        vb[nd] = *(const bf16x8*)&Vt[wid][(nd * 16 + fr) * 72 + ks * 32 + fq * 8];
#pragma unroll
      for (int mt = 0; mt < 4; ++mt)
#pragma unroll
        for (int nd = 0; nd < 2; ++nd)
          oacc[mt][nd] = mfma16(pa[mt], vb[nd], oacc[mt][nd]);
    }
#pragma unroll
    for (int mt = 0; mt < 4; ++mt)
#pragma unroll
      for (int nd = 0; nd < 2; ++nd)
#pragma unroll
        for (int jj = 0; jj < 4; ++jj)
          o[(size_t)(m * 64 + mt * 16 + fq * 4 + jj) * DIM_ + h * 32 + nd * 16 + fr] =
              f2bf(oacc[mt][nd][jj]);
  }
}

// ---------------- launch ----------------
extern "C" void kernel_launch(void* const* d_in, const int* in_sizes, int n_in,
                              void* d_out, int out_size, void* d_ws, size_t ws_size,
                              hipStream_t stream) {
  const float* x = (const float*)d_in[0];
  const int* iw = (const int*)d_in[1];
  const int* ip = (const int*)d_in[2];
  const int* blk = (const int*)d_in[3];
  const float* ln1w = (const float*)d_in[6];
  const float* ln1b = (const float*)d_in[7];
  const float* qkvw = (const float*)d_in[8];
  const float* qkvb = (const float*)d_in[9];
  const float* projw = (const float*)d_in[10];
  const float* projb = (const float*)d_in[11];
  const float* ln2w = (const float*)d_in[12];
  const float* ln2b = (const float*)d_in[13];
  const float* fc1w = (const float*)d_in[14];
  const float* fc1b = (const float*)d_in[15];
  const float* fc2w = (const float*)d_in[16];
  const float* fc2b = (const float*)d_in[17];
  float* out = (float*)d_out;

  char* ws = (char*)d_ws;
  short* w_all = (short*)ws;                 // 1,769,472 bf16
  short* w_qkv = w_all;
  short* w_proj = w_all + 442368;
  short* w_fc1 = w_all + 589824;
  short* w_fc2 = w_all + 1179648;
  int* inv_ip = (int*)(ws + 3538944);
  int* rowmap = inv_ip + NTOK_;
  int* win_rank = rowmap + NTOK_;
  unsigned* bitmap = (unsigned*)(win_rank + NW_);
  short* xp = (short*)(ws + 4349952);                        // 75.5 MB (also ln2 out)
  short* qkv_g = (short*)(ws + 4349952 + 75497472);          // 302 MB (qkv, then gelu t)
  short* obuf = (short*)(ws + 381837312);                    // 75.5 MB
  short* hbuf = (short*)(ws + 457334784);                    // 75.5 MB
  short* ln2buf = xp;
  (void)in_sizes; (void)n_in; (void)out_size; (void)ws_size;

  mapA_k<<<12, 256, 0, stream>>>(win_rank, bitmap);
  mapB_k<<<39, 256, 0, stream>>>(iw, blk, win_rank, bitmap);
  mapC_k<<<NTOK_ / 256, 256, 0, stream>>>(ip, iw, bitmap, inv_ip, rowmap);
  wconv_k<<<6912, 256, 0, stream>>>(qkvw, projw, fc1w, fc2w, w_all);
  ln1_k<<<(NW_ * 64) / 4, 256, 0, stream>>>(x, ln1w, ln1b, win_rank, inv_ip, bitmap,
                                            out, xp);
  gemm_k<0><<<768 * 9, 256, 0, stream>>>(xp, w_qkv, qkvb, 384, QKVD_, 9, qkv_g,
                                         nullptr, nullptr, nullptr);
  attn_k<<<WACT_, 256, 0, stream>>>(qkv_g, bitmap, ip, obuf);
  gemm_k<1><<<768 * 3, 256, 0, stream>>>(obuf, w_proj, projb, 384, DIM_, 3, hbuf,
                                         xp, nullptr, nullptr);
  ln2_k<<<NTOK_ / 4, 256, 0, stream>>>(hbuf, ln2w, ln2b, ln2buf);
  gemm_k<2><<<768 * 12, 256, 0, stream>>>(ln2buf, w_fc1, fc1b, 384, MLPD_, 12, qkv_g,
                                          nullptr, nullptr, nullptr);
  gemm_k<3><<<768 * 3, 256, 0, stream>>>(qkv_g, w_fc2, fc2b, 1536, DIM_, 3, nullptr,
                                         hbuf, rowmap, out);
}

// Round 8
// 874.072 us; speedup vs baseline: 1.3198x; 1.0305x over previous
//
#include <hip/hip_runtime.h>
#include <hip/hip_bf16.h>

typedef __attribute__((ext_vector_type(8))) short bf16x8;
typedef __attribute__((ext_vector_type(4))) float f32x4;

#define NW_   3072
#define WACT_ 1536
#define NTOK_ 98304
#define NBLK_ 9830
#define DIM_  384
#define QKVD_ 1152
#define MLPD_ 1536

__device__ __forceinline__ float bf2f(short s) {
  union { unsigned u; float f; } c;
  c.u = ((unsigned)(unsigned short)s) << 16;
  return c.f;
}
__device__ __forceinline__ short f2bf(float f) {
  union { float f; unsigned u; } c; c.f = f;
  unsigned lsb = (c.u >> 16) & 1u;
  c.u += 0x7fffu + lsb;
  return (short)(c.u >> 16);
}

__device__ __forceinline__ f32x4 mfma16(bf16x8 a, bf16x8 b, f32x4 c) {
  return __builtin_amdgcn_mfma_f32_16x16x32_bf16(a, b, c, 0, 0, 0);
}

__device__ __forceinline__ void gload16(const void* g, void* l) {
  __builtin_amdgcn_global_load_lds(
      (const __attribute__((address_space(1))) unsigned*)g,
      (__attribute__((address_space(3))) unsigned*)l, 16, 0, 0);
}

// ---------------- map kernels ----------------
__global__ __launch_bounds__(256) void mapA_k(int* win_rank, unsigned* bitmap) {
  int t = blockIdx.x * 256 + threadIdx.x;
  if (t < NW_) { win_rank[t] = -1; bitmap[t] = 0u; }
}

__global__ __launch_bounds__(256) void mapB_k(const int* __restrict__ iw,
                                              const int* __restrict__ blk,
                                              int* win_rank, unsigned* bitmap) {
  int t = blockIdx.x * 256 + threadIdx.x;
  if (t < WACT_) win_rank[iw[t]] = t;
  if (t < NBLK_) { int j = blk[t]; atomicOr(&bitmap[j >> 5], 1u << (j & 31)); }
}

__global__ __launch_bounds__(256) void mapC_k(const int* __restrict__ ip,
                                              const int* __restrict__ iw,
                                              const unsigned* __restrict__ bitmap,
                                              int* inv_ip, int* rowmap) {
  int i = blockIdx.x * 256 + threadIdx.x;
  if (i < NTOK_) {
    int j = ip[i];
    inv_ip[j] = i;
    int blocked = (bitmap[j >> 5] >> (j & 31)) & 1;
    rowmap[i] = blocked ? -1 : (iw[j >> 6] * 64 + (j & 63));
  }
}

// ---------------- weight conversion ----------------
__global__ __launch_bounds__(256) void wconv_k(const float* __restrict__ qkvw,
                                               const float* __restrict__ projw,
                                               const float* __restrict__ fc1w,
                                               const float* __restrict__ fc2w,
                                               short* __restrict__ dst) {
  int i = blockIdx.x * 256 + threadIdx.x;  // total 1,769,472
  float v;
  if (i < 442368) v = qkvw[i];
  else if (i < 589824) v = projw[i - 442368];
  else if (i < 1179648) v = fc1w[i - 589824];
  else v = fc2w[i - 1179648];
  dst[i] = f2bf(v);
}

// ---------------- LN1 + gather/permute ----------------
__global__ __launch_bounds__(256) void ln1_k(const float* __restrict__ x,
                                             const float* __restrict__ w,
                                             const float* __restrict__ b,
                                             const int* __restrict__ win_rank,
                                             const int* __restrict__ inv_ip,
                                             const unsigned* __restrict__ bitmap,
                                             float* __restrict__ out,
                                             short* __restrict__ xp) {
  int lane = threadIdx.x & 63;
  int tok = (blockIdx.x << 2) + (threadIdx.x >> 6);
  const float* xr = x + (size_t)tok * DIM_;
  float v[6]; float s = 0.f;
#pragma unroll
  for (int j = 0; j < 6; ++j) { v[j] = xr[lane + 64 * j]; s += v[j]; }
#pragma unroll
  for (int m = 1; m < 64; m <<= 1) s += __shfl_xor(s, m, 64);
  float mu = s * (1.0f / DIM_);
  float q = 0.f;
#pragma unroll
  for (int j = 0; j < 6; ++j) { float d = v[j] - mu; q += d * d; }
#pragma unroll
  for (int m = 1; m < 64; m <<= 1) q += __shfl_xor(q, m, 64);
  float rs = rsqrtf(q * (1.0f / DIM_) + 1e-5f);
  float y[6];
#pragma unroll
  for (int j = 0; j < 6; ++j)
    y[j] = (v[j] - mu) * rs * w[lane + 64 * j] + b[lane + 64 * j];
  int wdw = tok >> 6, t = tok & 63;
  int rank = win_rank[wdw];
  if (rank < 0) {
#pragma unroll
    for (int j = 0; j < 6; ++j) out[(size_t)tok * DIM_ + lane + 64 * j] = y[j];
  } else {
    int jdx = (rank << 6) + t;
    int i = inv_ip[jdx];
#pragma unroll
    for (int j = 0; j < 6; ++j) xp[(size_t)i * DIM_ + lane + 64 * j] = f2bf(y[j]);
    if ((bitmap[jdx >> 5] >> (jdx & 31)) & 1) {
#pragma unroll
      for (int j = 0; j < 6; ++j) out[(size_t)tok * DIM_ + lane + 64 * j] = y[j];
    }
  }
}

// ---------------- LN2 ----------------
__global__ __launch_bounds__(256) void ln2_k(const short* __restrict__ h,
                                             const float* __restrict__ w,
                                             const float* __restrict__ b,
                                             short* __restrict__ outln) {
  int lane = threadIdx.x & 63;
  int tok = (blockIdx.x << 2) + (threadIdx.x >> 6);
  const short* xr = h + (size_t)tok * DIM_;
  float v[6]; float s = 0.f;
#pragma unroll
  for (int j = 0; j < 6; ++j) { v[j] = bf2f(xr[lane + 64 * j]); s += v[j]; }
#pragma unroll
  for (int m = 1; m < 64; m <<= 1) s += __shfl_xor(s, m, 64);
  float mu = s * (1.0f / DIM_);
  float q = 0.f;
#pragma unroll
  for (int j = 0; j < 6; ++j) { float d = v[j] - mu; q += d * d; }
#pragma unroll
  for (int m = 1; m < 64; m <<= 1) q += __shfl_xor(q, m, 64);
  float rs = rsqrtf(q * (1.0f / DIM_) + 1e-5f);
#pragma unroll
  for (int j = 0; j < 6; ++j) {
    float y = (v[j] - mu) * rs * w[lane + 64 * j] + b[lane + 64 * j];
    outln[(size_t)tok * DIM_ + lane + 64 * j] = f2bf(y);
  }
}

// ---------------- GEMM: C = A * B^T ----------------
// 256(M)x128(N) tile, 8 waves (512 thr), single-buffer LDS (48 KB -> 3
// blocks/CU), __syncthreads pipeline, flat-grid XCD-chunk swizzle, bias in
// regs. Per-wave code identical to the 128^2 structure (64x64 sub-tile).
// Intensity 85 FLOP/staged-byte vs 64 at 128^2 (L1-staging-bound fix).
// EPI 0: +bias -> bf16 (ld N)        (QKV)
// EPI 1: +bias +add_bf -> bf16       (proj + residual -> h)
// EPI 2: +bias, fast gelu -> bf16    (fc1)
// EPI 3: +bias +add_bf, scatter fp32 (fc2 + residual -> out)
template <int EPI>
__global__ __launch_bounds__(512) void gemm_k(const short* __restrict__ A,
                                              const short* __restrict__ B,
                                              const float* __restrict__ bias,
                                              int K, int N, int nx,
                                              short* __restrict__ Cb,
                                              const short* __restrict__ add_bf,
                                              const int* __restrict__ rowmap,
                                              float* __restrict__ outf) {
  const int nwg = gridDim.x;
  const int q8 = nwg >> 3;
  const int wg = (blockIdx.x & 7) * q8 + (blockIdx.x >> 3);
  const int ntile = wg % nx, mtile = wg / nx;
  const int tid = threadIdx.x, wid = tid >> 6, lane = tid & 63;
  const int fq = lane >> 4, fr = lane & 15;
  const int wr = wid >> 1, wc = wid & 1;  // 4(M) x 2(N) waves, 64x64 each
  __shared__ __align__(16) short lA[256 * 64];
  __shared__ __align__(16) short lB[128 * 64];
  const int row0 = mtile * 256, col0 = ntile * 128;
  float bs[4];
#pragma unroll
  for (int nt = 0; nt < 4; ++nt) bs[nt] = bias[col0 + wc * 64 + nt * 16 + fr];
  f32x4 acc[4][4];
#pragma unroll
  for (int a = 0; a < 4; ++a)
#pragma unroll
    for (int c = 0; c < 4; ++c) acc[a][c] = (f32x4){0.f, 0.f, 0.f, 0.f};
  const int nkt = K >> 6;
  for (int kt = 0; kt < nkt; ++kt) {
    const int k0 = kt << 6;
    // A: 2048 16B-groups, B: 1024 -> 4 + 2 per thread
#pragma unroll
    for (int i = 0; i < 4; ++i) {
      int g = i * 512 + tid;
      int r = g >> 3, c8 = g & 7;
      int s8 = c8 ^ (r & 7);
      gload16(A + (size_t)(row0 + r) * K + k0 + s8 * 8, (char*)lA + (size_t)g * 16);
    }
#pragma unroll
    for (int i = 0; i < 2; ++i) {
      int g = i * 512 + tid;
      int r = g >> 3, c8 = g & 7;
      int s8 = c8 ^ (r & 7);
      gload16(B + (size_t)(col0 + r) * K + k0 + s8 * 8, (char*)lB + (size_t)g * 16);
    }
    __syncthreads();
#pragma unroll
    for (int ks = 0; ks < 2; ++ks) {
      bf16x8 af[4], bfr[4];
#pragma unroll
      for (int mt = 0; mt < 4; ++mt) {
        int r = wr * 64 + mt * 16 + fr;
        af[mt] = *(const bf16x8*)&lA[r * 64 + ((ks * 4 + fq) ^ (r & 7)) * 8];
      }
#pragma unroll
      for (int nt = 0; nt < 4; ++nt) {
        int r = wc * 64 + nt * 16 + fr;
        bfr[nt] = *(const bf16x8*)&lB[r * 64 + ((ks * 4 + fq) ^ (r & 7)) * 8];
      }
#pragma unroll
      for (int mt = 0; mt < 4; ++mt)
#pragma unroll
        for (int nt = 0; nt < 4; ++nt)
          acc[mt][nt] = mfma16(af[mt], bfr[nt], acc[mt][nt]);
    }
    __syncthreads();
  }
#pragma unroll
  for (int mt = 0; mt < 4; ++mt) {
#pragma unroll
    for (int jj = 0; jj < 4; ++jj) {
      int r = row0 + wr * 64 + mt * 16 + fq * 4 + jj;
      int dmap = 0;
      if (EPI == 3) dmap = rowmap[r];
#pragma unroll
      for (int nt = 0; nt < 4; ++nt) {
        int gcol = col0 + wc * 64 + nt * 16 + fr;
        float v = acc[mt][nt][jj] + bs[nt];
        if (EPI == 0) {
          Cb[(size_t)r * N + gcol] = f2bf(v);
        } else if (EPI == 1) {
          v += bf2f(add_bf[(size_t)r * DIM_ + gcol]);
          Cb[(size_t)r * DIM_ + gcol] = f2bf(v);
        } else if (EPI == 2) {
          // gelu(x) ~= x * sigmoid(2u), u = 0.79788456*(x + 0.044715 x^3)
          float u = v * (0.79788456f + 0.03567741f * v * v);
          float g = v * __builtin_amdgcn_rcpf(1.0f + __expf(-2.0f * u));
          Cb[(size_t)r * MLPD_ + gcol] = f2bf(g);
        } else {
          v += bf2f(add_bf[(size_t)r * DIM_ + gcol]);
          if (dmap >= 0) outf[(size_t)dmap * DIM_ + gcol] = v;
        }
      }
    }
  }
}

// ---------------- attention ----------------
__global__ __launch_bounds__(256) void attn_k(const short* __restrict__ qkv,
                                              const unsigned* __restrict__ bitmap,
                                              const int* __restrict__ ip,
                                              short* __restrict__ o) {
  const int m = blockIdx.x;
  const int wid = threadIdx.x >> 6, lane = threadIdx.x & 63;
  const int fq = lane >> 4, fr = lane & 15;
  __shared__ __align__(16) short P[4][64 * 72];
  __shared__ __align__(16) short Vt[4][32 * 72];
  __shared__ unsigned char flags[64];
  if (threadIdx.x < 64) {
    int j = ip[m * 64 + threadIdx.x];
    flags[threadIdx.x] = (unsigned char)((bitmap[j >> 5] >> (j & 31)) & 1);
  }
  __syncthreads();
  const float scale = 0.17677669529663687f;
  int msk[4];
#pragma unroll
  for (int nt = 0; nt < 4; ++nt) msk[nt] = flags[nt * 16 + fr];

  for (int hh = 0; hh < 3; ++hh) {
    int h = wid * 3 + hh;
    const short* base = qkv + (size_t)m * 64 * QKVD_ + h * 96;
    f32x4 sacc[4][4];
#pragma unroll
    for (int a = 0; a < 4; ++a)
#pragma unroll
      for (int c = 0; c < 4; ++c) sacc[a][c] = (f32x4){0.f, 0.f, 0.f, 0.f};
    bf16x8 qa[4], kb[4];
#pragma unroll
    for (int mt = 0; mt < 4; ++mt)
      qa[mt] = *(const bf16x8*)(base + (size_t)(mt * 16 + fr) * QKVD_ + fq * 8);
#pragma unroll
    for (int nt = 0; nt < 4; ++nt)
      kb[nt] = *(const bf16x8*)(base + (size_t)(nt * 16 + fr) * QKVD_ + 32 + fq * 8);
#pragma unroll
    for (int mt = 0; mt < 4; ++mt)
#pragma unroll
      for (int nt = 0; nt < 4; ++nt)
        sacc[mt][nt] = mfma16(qa[mt], kb[nt], sacc[mt][nt]);
#pragma unroll
    for (int c = 0; c < 4; ++c) {
      bf16x8 vv = *(const bf16x8*)(base + (size_t)lane * QKVD_ + 64 + c * 8);
#pragma unroll
      for (int e = 0; e < 8; ++e) Vt[wid][(c * 8 + e) * 72 + lane] = vv[e];
    }
#pragma unroll
    for (int mt = 0; mt < 4; ++mt)
#pragma unroll
      for (int nt = 0; nt < 4; ++nt) {
        f32x4 sv = sacc[mt][nt];
#pragma unroll
        for (int jj = 0; jj < 4; ++jj)
          sv[jj] = msk[nt] ? -10000.0f : sv[jj] * scale;
        sacc[mt][nt] = sv;
      }
#pragma unroll
    for (int mt = 0; mt < 4; ++mt) {
#pragma unroll
      for (int jj = 0; jj < 4; ++jj) {
        float mx = sacc[mt][0][jj];
#pragma unroll
        for (int nt = 1; nt < 4; ++nt) mx = fmaxf(mx, sacc[mt][nt][jj]);
#pragma unroll
        for (int mm = 1; mm < 16; mm <<= 1) mx = fmaxf(mx, __shfl_xor(mx, mm, 64));
        float sm = 0.f;
        float p[4];
#pragma unroll
        for (int nt = 0; nt < 4; ++nt) {
          p[nt] = __expf(sacc[mt][nt][jj] - mx);
          sm += p[nt];
        }
#pragma unroll
        for (int mm = 1; mm < 16; mm <<= 1) sm += __shfl_xor(sm, mm, 64);
        float inv = 1.0f / sm;
        int rowb = (mt * 16 + fq * 4 + jj) * 72;
#pragma unroll
        for (int nt = 0; nt < 4; ++nt)
          P[wid][rowb + nt * 16 + fr] = f2bf(p[nt] * inv);
      }
    }
    f32x4 oacc[4][2];
#pragma unroll
    for (int a = 0; a < 4; ++a)
#pragma unroll
      for (int c = 0; c < 2; ++c) oacc[a][c] = (f32x4){0.f, 0.f, 0.f, 0.f};
#pragma unroll
    for (int ks = 0; ks < 2; ++ks) {
      bf16x8 pa[4], vb[2];
#pragma unroll
      for (int mt = 0; mt < 4; ++mt)
        pa[mt] = *(const bf16x8*)&P[wid][(mt * 16 + fr) * 72 + ks * 32 + fq * 8];
#pragma unroll
      for (int nd = 0; nd < 2; ++nd)
        vb[nd] = *(const bf16x8*)&Vt[wid][(nd * 16 + fr) * 72 + ks * 32 + fq * 8];
#pragma unroll
      for (int mt = 0; mt < 4; ++mt)
#pragma unroll
        for (int nd = 0; nd < 2; ++nd)
          oacc[mt][nd] = mfma16(pa[mt], vb[nd], oacc[mt][nd]);
    }
#pragma unroll
    for (int mt = 0; mt < 4; ++mt)
#pragma unroll
      for (int nd = 0; nd < 2; ++nd)
#pragma unroll
        for (int jj = 0; jj < 4; ++jj)
          o[(size_t)(m * 64 + mt * 16 + fq * 4 + jj) * DIM_ + h * 32 + nd * 16 + fr] =
              f2bf(oacc[mt][nd][jj]);
  }
}

// ---------------- launch ----------------
extern "C" void kernel_launch(void* const* d_in, const int* in_sizes, int n_in,
                              void* d_out, int out_size, void* d_ws, size_t ws_size,
                              hipStream_t stream) {
  const float* x = (const float*)d_in[0];
  const int* iw = (const int*)d_in[1];
  const int* ip = (const int*)d_in[2];
  const int* blk = (const int*)d_in[3];
  const float* ln1w = (const float*)d_in[6];
  const float* ln1b = (const float*)d_in[7];
  const float* qkvw = (const float*)d_in[8];
  const float* qkvb = (const float*)d_in[9];
  const float* projw = (const float*)d_in[10];
  const float* projb = (const float*)d_in[11];
  const float* ln2w = (const float*)d_in[12];
  const float* ln2b = (const float*)d_in[13];
  const float* fc1w = (const float*)d_in[14];
  const float* fc1b = (const float*)d_in[15];
  const float* fc2w = (const float*)d_in[16];
  const float* fc2b = (const float*)d_in[17];
  float* out = (float*)d_out;

  char* ws = (char*)d_ws;
  short* w_all = (short*)ws;                 // 1,769,472 bf16
  short* w_qkv = w_all;
  short* w_proj = w_all + 442368;
  short* w_fc1 = w_all + 589824;
  short* w_fc2 = w_all + 1179648;
  int* inv_ip = (int*)(ws + 3538944);
  int* rowmap = inv_ip + NTOK_;
  int* win_rank = rowmap + NTOK_;
  unsigned* bitmap = (unsigned*)(win_rank + NW_);
  short* xp = (short*)(ws + 4349952);                        // 75.5 MB (also ln2 out)
  short* qkv_g = (short*)(ws + 4349952 + 75497472);          // 302 MB (qkv, then gelu t)
  short* obuf = (short*)(ws + 381837312);                    // 75.5 MB
  short* hbuf = (short*)(ws + 457334784);                    // 75.5 MB
  short* ln2buf = xp;
  (void)in_sizes; (void)n_in; (void)out_size; (void)ws_size;

  mapA_k<<<12, 256, 0, stream>>>(win_rank, bitmap);
  mapB_k<<<39, 256, 0, stream>>>(iw, blk, win_rank, bitmap);
  mapC_k<<<NTOK_ / 256, 256, 0, stream>>>(ip, iw, bitmap, inv_ip, rowmap);
  wconv_k<<<6912, 256, 0, stream>>>(qkvw, projw, fc1w, fc2w, w_all);
  ln1_k<<<(NW_ * 64) / 4, 256, 0, stream>>>(x, ln1w, ln1b, win_rank, inv_ip, bitmap,
                                            out, xp);
  // mtiles = 98304/256 = 384; grid = 384 * nx (all % 8 == 0)
  gemm_k<0><<<384 * 9, 512, 0, stream>>>(xp, w_qkv, qkvb, 384, QKVD_, 9, qkv_g,
                                         nullptr, nullptr, nullptr);
  attn_k<<<WACT_, 256, 0, stream>>>(qkv_g, bitmap, ip, obuf);
  gemm_k<1><<<384 * 3, 512, 0, stream>>>(obuf, w_proj, projb, 384, DIM_, 3, hbuf,
                                         xp, nullptr, nullptr);
  ln2_k<<<NTOK_ / 4, 256, 0, stream>>>(hbuf, ln2w, ln2b, ln2buf);
  gemm_k<2><<<384 * 12, 512, 0, stream>>>(ln2buf, w_fc1, fc1b, 384, MLPD_, 12, qkv_g,
                                          nullptr, nullptr, nullptr);
  gemm_k<3><<<384 * 3, 512, 0, stream>>>(qkv_g, w_fc2, fc2b, 1536, DIM_, 3, nullptr,
                                         hbuf, rowmap, out);
}